// Round 2
// baseline (449.303 us; speedup 1.0000x reference)
//
#include <hip/hip_runtime.h>
#include <hip/hip_bf16.h>
#include <cstdint>
#include <cstddef>

// Shapes: B=2, S=512, C=25, H=768, 2H=1536, 3H=2304, 4H=3072
#define BB 2
#define SS 512
#define CC 25
#define HH 768
#define H2 1536
#define H3 2304
#define H4 3072
// chunked layout: [kc][row][8] bf16, kc = k/8
#define XC_STRIDE ((size_t)96 * 512 * 8)   // per-bc X slab, 96 chunks x 512 rows

typedef __attribute__((ext_vector_type(8))) short bf16x8;
typedef __attribute__((ext_vector_type(4))) float f32x4;

#define DEVINL static __device__ __forceinline__

DEVINL unsigned short f2bf(float f) {
  union { float f; unsigned u; } v; v.f = f;
  unsigned r = v.u + 0x7FFF + ((v.u >> 16) & 1);  // RNE
  return (unsigned short)(r >> 16);
}
DEVINL float bf2f(unsigned short b) {
  union { unsigned u; float f; } v; v.u = ((unsigned)b) << 16; return v.f;
}

DEVINL void async16(const void* g, void* l) {
  __builtin_amdgcn_global_load_lds(
      (const __attribute__((address_space(1))) void*)g,
      (__attribute__((address_space(3))) void*)l, 16, 0, 0);
}

// raw barrier (no implicit waitcnt drain) with compiler reorder fence
#define BAR() do { asm volatile("" ::: "memory"); \
                   __builtin_amdgcn_s_barrier();  \
                   asm volatile("" ::: "memory"); } while (0)
#define MFMA16(a, b, c) __builtin_amdgcn_mfma_f32_16x16x32_bf16(a, b, c, 0, 0, 0)

// ---------------- K1: all casts/chunking + out init (5316 blocks) ----------
__global__ void k_prep(const float* __restrict__ token,
                       const float* __restrict__ label,
                       const float* __restrict__ b2,
                       const float* __restrict__ Wt,
                       const float* __restrict__ Wl,
                       const float* __restrict__ W1,
                       unsigned short* __restrict__ TC,
                       unsigned short* __restrict__ LC,
                       float* __restrict__ out,
                       unsigned short* __restrict__ WtC,
                       unsigned short* __restrict__ WlC,
                       unsigned short* __restrict__ W1C) {
  __shared__ float tile[64][33];
  const int bid = blockIdx.x;
  const int tid = threadIdx.x;
  if (bid < 408) {
    const float* in;
    unsigned short* o;
    int R, RP, kt, rt;
    if (bid < 384) {
      in = token; o = TC; R = 1024; RP = 1024; kt = bid % 24; rt = bid / 24;
    } else {
      in = label; o = LC; R = 50; RP = 64; kt = bid - 384; rt = 0;
    }
    const int k0 = kt * 32, r0 = rt * 64;
    const int tx = tid & 31, ty = tid >> 5;
#pragma unroll
    for (int i = 0; i < 8; i++) {
      int r = r0 + ty + i * 8;
      tile[ty + i * 8][tx] = in[(size_t)min(r, R - 1) * HH + k0 + tx];
    }
    __syncthreads();
    const int rl = tid & 63, kcl = tid >> 6;
    bf16x8 ov;
#pragma unroll
    for (int j = 0; j < 8; j++) ov[j] = (short)f2bf(tile[rl][kcl * 8 + j]);
    *(bf16x8*)&o[((size_t)((k0 >> 3) + kcl) * RP + r0 + rl) * 8] = ov;
  } else if (bid < 708) {
    int i = (bid - 408) * 256 + tid;
    if (i < BB * SS * CC * 3) out[i] = b2[i % 3];
  } else {
    const int wb = bid - 708;
    const float* in;
    unsigned short* o;
    int N, bx, by;
    if (wb < 3456) {
      in = W1; o = W1C; N = H4; bx = wb % 48; by = wb / 48;
    } else if (wb < 4032) {
      int b = wb - 3456; in = Wt; o = WtC; N = H2; bx = b % 24; by = b / 24;
    } else {
      int b = wb - 4032; in = Wl; o = WlC; N = H2; bx = b % 24; by = b / 24;
    }
    const int f = bx * 64 + (tid & 63);
    const int hc = by * 4 + (tid >> 6);
    bf16x8 ov;
#pragma unroll
    for (int j = 0; j < 8; j++)
      ov[j] = (short)f2bf(in[(size_t)(hc * 8 + j) * N + f]);
    *(bf16x8*)&o[((size_t)hc * N + f) * 8] = ov;
  }
}

// ---------------- shared K-loop: 128x128 tile, K=768, chunked operands -----
DEVINL void mm_kloop(const unsigned short* __restrict__ Ab, int NRA, int MA,
                     int m0, const unsigned short* __restrict__ Bt, int NRB,
                     int n0, unsigned short* As, unsigned short* Bs,
                     f32x4 (&acc)[4][4]) {
  const int tid = threadIdx.x;
  const int lane = tid & 63;
  const int wave = tid >> 6;
  const int q = lane >> 4;
  const int li = lane & 15;
  const int wm = (wave >> 1) * 64;
  const int wn = (wave & 1) * 64;

  int sr[4], skc[4], sra[4];
#pragma unroll
  for (int j = 0; j < 4; j++) {
    int slot = j * 256 + tid;
    skc[j] = slot >> 7;
    sr[j] = slot & 127;
    sra[j] = min(m0 + sr[j], MA - 1);
  }
  auto stage = [&](int kciter) {
#pragma unroll
    for (int j = 0; j < 4; j++) {
      int slot = j * 256 + tid;
      async16(Ab + ((size_t)(kciter + skc[j]) * NRA + sra[j]) * 8,
              (char*)As + slot * 16);
      async16(Bt + ((size_t)(kciter + skc[j]) * NRB + n0 + sr[j]) * 8,
              (char*)Bs + slot * 16);
    }
  };

  stage(0);
  for (int it = 0; it < 12; it++) {
    __syncthreads();  // stage landed
#pragma unroll
    for (int ks = 0; ks < 2; ks++) {
      bf16x8 af[4], bb[4];
#pragma unroll
      for (int mi = 0; mi < 4; mi++)
        af[mi] = *(const bf16x8*)&As[((ks * 4 + q) * 128 + wm + mi * 16 + li) * 8];
#pragma unroll
      for (int ni = 0; ni < 4; ni++)
        bb[ni] = *(const bf16x8*)&Bs[((ks * 4 + q) * 128 + wn + ni * 16 + li) * 8];
#pragma unroll
      for (int mi = 0; mi < 4; mi++)
#pragma unroll
        for (int ni = 0; ni < 4; ni++)
          acc[mi][ni] = MFMA16(af[mi], bb[ni], acc[mi][ni]);
    }
    __syncthreads();  // all reads done
    if (it + 1 < 12) stage((it + 1) * 8);
  }
}

// ---------------- K2: G1+G2 fused (108 blocks) ----------------
__global__ __launch_bounds__(256, 4) void k_mm1(
    const unsigned short* __restrict__ TC, const unsigned short* __restrict__ LC,
    const unsigned short* __restrict__ WtC, const unsigned short* __restrict__ WlC,
    const float* __restrict__ bt, const float* __restrict__ bl,
    unsigned short* __restrict__ TP, unsigned short* __restrict__ LP) {
  __shared__ __align__(16) unsigned short As[8 * 128 * 8];
  __shared__ __align__(16) unsigned short Bs[8 * 128 * 8];
  const int bid = blockIdx.x;
  const int nt = bid % 12, my = bid / 12;
  const bool tok = my < 8;
  const unsigned short* A = tok ? TC : LC;
  const unsigned short* Bt = tok ? WtC : WlC;
  const float* bias = tok ? bt : bl;
  unsigned short* C = tok ? TP : LP;
  const int NRA = tok ? 1024 : 64, MA = tok ? 1024 : 50;
  const int m0 = tok ? my * 128 : 0;
  const int ldc = NRA;
  const int n0 = nt * 128;

  f32x4 acc[4][4];
#pragma unroll
  for (int i = 0; i < 4; i++)
#pragma unroll
    for (int j = 0; j < 4; j++) acc[i][j] = (f32x4){0.f, 0.f, 0.f, 0.f};
  mm_kloop(A, NRA, MA, m0, Bt, H2, n0, As, Bs, acc);

  const int lane = threadIdx.x & 63, wave = threadIdx.x >> 6;
  const int q = lane >> 4, li = lane & 15;
  const int wm = (wave >> 1) * 64, wn = (wave & 1) * 64;
#pragma unroll
  for (int mi = 0; mi < 4; mi++)
#pragma unroll
    for (int rr = 0; rr < 4; rr++) {
      int row = m0 + wm + mi * 16 + q * 4 + rr;
      if (row < MA) {
#pragma unroll
        for (int ni = 0; ni < 4; ni++) {
          int col = n0 + wn + ni * 16 + li;
          C[((size_t)(col >> 3) * ldc + row) * 8 + (col & 7)] =
              f2bf(acc[mi][ni][rr] + bias[col]);
        }
      }
    }
}

// ---------------- K3: G3+G4 (216 blocks) + make_x (9600 blocks) ----------------
__global__ __launch_bounds__(256, 4) void k_mm2(
    const unsigned short* __restrict__ TP, const unsigned short* __restrict__ LP,
    const unsigned short* __restrict__ W1C,
    float* __restrict__ base, float* __restrict__ al,
    unsigned short* __restrict__ XC) {
  __shared__ __align__(16) unsigned short As[8 * 128 * 8];
  __shared__ __align__(16) unsigned short Bs[8 * 128 * 8];
  const int bid = blockIdx.x;
  if (bid < 216) {
    const int nt = bid % 24, my = bid / 24;
    const bool tok = my < 8;
    const unsigned short* A = tok ? TP : LP;
    const unsigned short* Bt = tok ? W1C : W1C + (size_t)96 * H4 * 8;
    float* Cf = tok ? base : al;
    const int NRA = tok ? 1024 : 64, MA = tok ? 1024 : 50;
    const int m0 = tok ? my * 128 : 0;
    const int n0 = nt * 128;

    f32x4 acc[4][4];
#pragma unroll
    for (int i = 0; i < 4; i++)
#pragma unroll
      for (int j = 0; j < 4; j++) acc[i][j] = (f32x4){0.f, 0.f, 0.f, 0.f};
    mm_kloop(A, NRA, MA, m0, Bt, H4, n0, As, Bs, acc);

    const int lane = threadIdx.x & 63, wave = threadIdx.x >> 6;
    const int q = lane >> 4, li = lane & 15;
    const int wm = (wave >> 1) * 64, wn = (wave & 1) * 64;
#pragma unroll
    for (int mi = 0; mi < 4; mi++)
#pragma unroll
      for (int rr = 0; rr < 4; rr++) {
        int row = m0 + wm + mi * 16 + q * 4 + rr;
        if (row < MA) {
#pragma unroll
          for (int ni = 0; ni < 4; ni++) {
            int col = n0 + wn + ni * 16 + li;
            Cf[(size_t)row * H4 + col] = acc[mi][ni][rr];
          }
        }
      }
  } else {
    // make_x: XC[bc][hc][s][8] = tb_chunk(96+hc)[b*512+s] * lb_chunk(96+hc)[bc]
    const int i = bid - 216;           // 0..9599
    const int bc = i / 192;
    const int rem = i % 192;
    const int hc = rem >> 1;
    const int s = (rem & 1) * 256 + threadIdx.x;
    const int b = bc / CC;
    bf16x8 tv = *(const bf16x8*)&TP[((size_t)(96 + hc) * 1024 + b * 512 + s) * 8];
    bf16x8 lv = *(const bf16x8*)&LP[((size_t)(96 + hc) * 64 + bc) * 8];
    bf16x8 o;
#pragma unroll
    for (int j = 0; j < 8; j++)
      o[j] = (short)f2bf(bf2f((unsigned short)tv[j]) * bf2f((unsigned short)lv[j]));
    *(bf16x8*)&XC[(size_t)bc * XC_STRIDE + ((size_t)hc * 512 + s) * 8] = o;
  }
}

// ---------------- K4: G5 scorer, 256x256 8-phase schedule (grid 12 x 100) ----
// 512 threads = 8 waves (2M x 4N); wave tile 128x64, acc[8][4].
// BK=64 (8 kc), 12 K-tiles, double-buffered K-tiles (128 KB LDS).
// Per tile: 4 phases (ks, n-half), each {ds_read subtile; stage 1 half-tile
// (2 global_load_lds); barrier; setprio(1) 16 MFMA setprio(0); barrier}.
// Counted vmcnt(4) before the closing barriers of ph1/ph3 only; per-wave
// outstanding-load FIFO stays 4-8, drains to 0 only in the last tile.
__global__ __launch_bounds__(512, 2) void k_scorer(
    const unsigned short* __restrict__ XC,   // per-bc slabs [96][512][8]
    const unsigned short* __restrict__ Bt,   // W1p chunked [96][3072][8]
    const float* __restrict__ base, const float* __restrict__ al,
    const float* __restrict__ b1, const float* __restrict__ W2,
    float* __restrict__ out) {
  __shared__ __align__(16) unsigned short As[2][8 * 256 * 8];  // 2 x 32 KB
  __shared__ __align__(16) unsigned short Bs[2][8 * 256 * 8];  // 2 x 32 KB
  const int tid = threadIdx.x;
  const int lane = tid & 63;
  const int wave = tid >> 6;
  const int q = lane >> 4;
  const int li = lane & 15;
  const int wm = (wave >> 2) * 128;        // 2 waves in M
  const int wn = (wave & 3) * 64;          // 4 waves in N

  const int n0 = blockIdx.x * 256;
  const int bc = blockIdx.y >> 1;
  const int m0 = (blockIdx.y & 1) * 256;
  const unsigned short* Ab = XC + (size_t)bc * XC_STRIDE;

  // half-tile staging: 16 KB = 1024 slots of 16B; 2 slots/thread.
  // slot -> (kc-local = slot>>8, row = slot&255); lane-consecutive = LDS-
  // consecutive (global_load_lds wave-linear dest requirement).
  auto stageA = [&](int t, int h) {
    const int kcb = t * 8 + h * 4;
    unsigned short* dst = &As[t & 1][h * 4 * 256 * 8];
#pragma unroll
    for (int j = 0; j < 2; j++) {
      int slot = j * 512 + tid;
      int kcl = slot >> 8, r = slot & 255;
      async16(Ab + ((size_t)(kcb + kcl) * 512 + m0 + r) * 8,
              (char*)dst + slot * 16);
    }
  };
  auto stageB = [&](int t, int h) {
    const int kcb = t * 8 + h * 4;
    unsigned short* dst = &Bs[t & 1][h * 4 * 256 * 8];
#pragma unroll
    for (int j = 0; j < 2; j++) {
      int slot = j * 512 + tid;
      int kcl = slot >> 8, r = slot & 255;
      async16(Bt + ((size_t)(kcb + kcl) * 3072 + n0 + r) * 8,
              (char*)dst + slot * 16);
    }
  };

  f32x4 acc[8][4];
#pragma unroll
  for (int i = 0; i < 8; i++)
#pragma unroll
    for (int j = 0; j < 4; j++) acc[i][j] = (f32x4){0.f, 0.f, 0.f, 0.f};

  // prologue: tile 0's four half-tiles in flight; drain first K-half only
  stageA(0, 0); stageB(0, 0); stageA(0, 1); stageB(0, 1);
  asm volatile("s_waitcnt vmcnt(4)" ::: "memory");
  BAR();

  bf16x8 af[8], bb[4];
  auto do_tile = [&](int t, const unsigned short* Ad, const unsigned short* Bd) {
    const bool iss = (t + 1 < 12);
    // ---- ph0: ks=0, nh=0 — reads A-Kh0 + B-Kh0 (drained at prev boundary)
#pragma unroll
    for (int mi = 0; mi < 8; mi++)
      af[mi] = *(const bf16x8*)&Ad[((0 + q) * 256 + wm + mi * 16 + li) * 8];
    bb[0] = *(const bf16x8*)&Bd[((0 + q) * 256 + wn + 0 * 16 + li) * 8];
    bb[1] = *(const bf16x8*)&Bd[((0 + q) * 256 + wn + 1 * 16 + li) * 8];
    if (iss) stageA(t + 1, 0);
    BAR();
    __builtin_amdgcn_s_setprio(1);
#pragma unroll
    for (int mi = 0; mi < 8; mi++) {
      acc[mi][0] = MFMA16(af[mi], bb[0], acc[mi][0]);
      acc[mi][1] = MFMA16(af[mi], bb[1], acc[mi][1]);
    }
    __builtin_amdgcn_s_setprio(0);
    BAR();
    // ---- ph1: ks=0, nh=1
    bb[2] = *(const bf16x8*)&Bd[((0 + q) * 256 + wn + 2 * 16 + li) * 8];
    bb[3] = *(const bf16x8*)&Bd[((0 + q) * 256 + wn + 3 * 16 + li) * 8];
    if (iss) stageB(t + 1, 0);
    BAR();
    __builtin_amdgcn_s_setprio(1);
#pragma unroll
    for (int mi = 0; mi < 8; mi++) {
      acc[mi][2] = MFMA16(af[mi], bb[2], acc[mi][2]);
      acc[mi][3] = MFMA16(af[mi], bb[3], acc[mi][3]);
    }
    __builtin_amdgcn_s_setprio(0);
    if (iss) { asm volatile("s_waitcnt vmcnt(4)" ::: "memory"); }
    else     { asm volatile("s_waitcnt vmcnt(0)" ::: "memory"); }
    BAR();
    // ---- ph2: ks=1, nh=0 — reads A-Kh1 + B-Kh1 (just drained by all waves)
#pragma unroll
    for (int mi = 0; mi < 8; mi++)
      af[mi] = *(const bf16x8*)&Ad[((4 + q) * 256 + wm + mi * 16 + li) * 8];
    bb[0] = *(const bf16x8*)&Bd[((4 + q) * 256 + wn + 0 * 16 + li) * 8];
    bb[1] = *(const bf16x8*)&Bd[((4 + q) * 256 + wn + 1 * 16 + li) * 8];
    if (iss) stageA(t + 1, 1);
    BAR();
    __builtin_amdgcn_s_setprio(1);
#pragma unroll
    for (int mi = 0; mi < 8; mi++) {
      acc[mi][0] = MFMA16(af[mi], bb[0], acc[mi][0]);
      acc[mi][1] = MFMA16(af[mi], bb[1], acc[mi][1]);
    }
    __builtin_amdgcn_s_setprio(0);
    BAR();
    // ---- ph3: ks=1, nh=1
    bb[2] = *(const bf16x8*)&Bd[((4 + q) * 256 + wn + 2 * 16 + li) * 8];
    bb[3] = *(const bf16x8*)&Bd[((4 + q) * 256 + wn + 3 * 16 + li) * 8];
    if (iss) stageB(t + 1, 1);
    BAR();
    __builtin_amdgcn_s_setprio(1);
#pragma unroll
    for (int mi = 0; mi < 8; mi++) {
      acc[mi][2] = MFMA16(af[mi], bb[2], acc[mi][2]);
      acc[mi][3] = MFMA16(af[mi], bb[3], acc[mi][3]);
    }
    __builtin_amdgcn_s_setprio(0);
    if (iss) { asm volatile("s_waitcnt vmcnt(4)" ::: "memory"); }
    else     { asm volatile("s_waitcnt vmcnt(0)" ::: "memory"); }
    BAR();
  };

#pragma unroll 1
  for (int tt = 0; tt < 6; tt++) {
    do_tile(2 * tt,     &As[0][0], &Bs[0][0]);
    do_tile(2 * tt + 1, &As[1][0], &Bs[1][0]);
  }

  // epilogue: E = acc + base + al + b1; relu; out += E @ W2 via MFMA.
  // Scratch in As[0] (last tile read only As[1]/Bs[1] — disjoint).
  const int b = bc / CC, c = bc % CC;
  int fcol[4];
  float alb[4];
#pragma unroll
  for (int ni = 0; ni < 4; ni++) {
    int f = n0 + wn + ni * 16 + li;
    fcol[ni] = f;
    alb[ni] = al[(size_t)bc * H4 + f] + b1[f];
  }
  bf16x8 w2f[2];
#pragma unroll
  for (int ks = 0; ks < 2; ks++)
#pragma unroll
    for (int jj = 0; jj < 8; jj++) {
      int f = n0 + wn + ks * 32 + q * 8 + jj;
      float v = (li < 3) ? W2[(size_t)f * 3 + li] : 0.f;
      w2f[ks][jj] = (short)f2bf(v);
    }
  unsigned short* Ew = &As[0][0] + wave * 1152;  // 2304 B per wave

#pragma unroll
  for (int mi = 0; mi < 8; mi++) {
    float bsv[4][4];
#pragma unroll
    for (int rr = 0; rr < 4; rr++) {
      int s_l = m0 + wm + mi * 16 + q * 4 + rr;
      const float* bp = base + (size_t)(b * SS + s_l) * H4;
#pragma unroll
      for (int ni = 0; ni < 4; ni++) bsv[ni][rr] = bp[fcol[ni]];
    }
#pragma unroll
    for (int rr = 0; rr < 4; rr++)
#pragma unroll
      for (int ni = 0; ni < 4; ni++) {
        float v = acc[mi][ni][rr] + bsv[ni][rr] + alb[ni];
        v = fmaxf(v, 0.f);
        Ew[(q * 4 + rr) * 72 + ni * 16 + li] = f2bf(v);
      }
    f32x4 oc = (f32x4){0.f, 0.f, 0.f, 0.f};
#pragma unroll
    for (int ks = 0; ks < 2; ks++) {
      bf16x8 ef = *(const bf16x8*)&Ew[li * 72 + ks * 32 + q * 8];
      oc = MFMA16(ef, w2f[ks], oc);
    }
#pragma unroll
    for (int rr = 0; rr < 4; rr++) {
      int s_l = m0 + wm + mi * 16 + q * 4 + rr;
      if (li < 3)
        atomicAdd(&out[((size_t)(b * SS + s_l) * CC + c) * 3 + li], oc[rr]);
    }
  }
}

// ---------------- host launch ----------------

extern "C" void kernel_launch(void* const* d_in, const int* in_sizes, int n_in,
                              void* d_out, int out_size, void* d_ws, size_t ws_size,
                              hipStream_t stream) {
  (void)in_sizes; (void)n_in; (void)ws_size; (void)out_size;
  const float* token = (const float*)d_in[0];
  const float* label = (const float*)d_in[1];
  const float* Wt    = (const float*)d_in[2];
  const float* bt    = (const float*)d_in[3];
  const float* Wl    = (const float*)d_in[4];
  const float* bl    = (const float*)d_in[5];
  const float* W1    = (const float*)d_in[6];
  const float* b1    = (const float*)d_in[7];
  const float* W2    = (const float*)d_in[8];
  const float* b2    = (const float*)d_in[9];
  float* out = (float*)d_out;

  char* p = (char*)d_ws;
  auto alloc = [&](size_t bytes) {
    char* r = p;
    p += (bytes + 255) & ~(size_t)255;
    return r;
  };
  unsigned short* TC  = (unsigned short*)alloc((size_t)96 * 1024 * 8 * 2);
  unsigned short* LC  = (unsigned short*)alloc((size_t)96 * 64 * 8 * 2);
  unsigned short* WtC = (unsigned short*)alloc((size_t)96 * 1536 * 8 * 2);
  unsigned short* WlC = (unsigned short*)alloc((size_t)96 * 1536 * 8 * 2);
  unsigned short* W1C = (unsigned short*)alloc((size_t)288 * 3072 * 8 * 2);
  unsigned short* TP  = (unsigned short*)alloc((size_t)192 * 1024 * 8 * 2);
  unsigned short* LP  = (unsigned short*)alloc((size_t)192 * 64 * 8 * 2);
  unsigned short* XC  = (unsigned short*)alloc((size_t)CC * BB * XC_STRIDE * 2);
  float* base = (float*)alloc((size_t)BB * SS * H4 * 4);
  float* al   = (float*)alloc((size_t)BB * CC * H4 * 4);

  // K1: all casts/chunking + out init
  k_prep<<<5316, 256, 0, stream>>>(token, label, b2, Wt, Wl, W1,
                                   TC, LC, out, WtC, WlC, W1C);
  // K2: G1+G2 fused projections
  k_mm1<<<108, 256, 0, stream>>>(TC, LC, WtC, WlC, bt, bl, TP, LP);
  // K3: G3+G4 GEMMs + make_x
  k_mm2<<<9816, 256, 0, stream>>>(TP, LP, W1C, base, al, XC);
  // K4: G5 scorer, 256x256 8-phase
  k_scorer<<<dim3(12, 100), 512, 0, stream>>>(
      XC, W1C + (size_t)192 * H4 * 8, base, al, b1, W2, out);
}

// Round 3
// 306.799 us; speedup vs baseline: 1.4645x; 1.4645x over previous
//
#include <hip/hip_runtime.h>
#include <hip/hip_bf16.h>
#include <cstdint>
#include <cstddef>

// Shapes: B=2, S=512, C=25, H=768, 2H=1536, 3H=2304, 4H=3072
#define BB 2
#define SS 512
#define CC 25
#define HH 768
#define H2 1536
#define H3 2304
#define H4 3072
// chunked layout: [kc][row][8] bf16, kc = k/8
#define XC_STRIDE ((size_t)96 * 512 * 8)   // per-bc X slab, 96 chunks x 512 rows

typedef __attribute__((ext_vector_type(8))) short bf16x8;
typedef __attribute__((ext_vector_type(4))) float f32x4;

#define DEVINL static __device__ __forceinline__

DEVINL unsigned short f2bf(float f) {
  union { float f; unsigned u; } v; v.f = f;
  unsigned r = v.u + 0x7FFF + ((v.u >> 16) & 1);  // RNE
  return (unsigned short)(r >> 16);
}
DEVINL float bf2f(unsigned short b) {
  union { unsigned u; float f; } v; v.u = ((unsigned)b) << 16; return v.f;
}

DEVINL void async16(const void* g, void* l) {
  __builtin_amdgcn_global_load_lds(
      (const __attribute__((address_space(1))) void*)g,
      (__attribute__((address_space(3))) void*)l, 16, 0, 0);
}

// raw barrier (no implicit waitcnt drain) with compiler reorder fence
#define BAR() do { asm volatile("" ::: "memory"); \
                   __builtin_amdgcn_s_barrier();  \
                   asm volatile("" ::: "memory"); } while (0)
#define MFMA16(a, b, c) __builtin_amdgcn_mfma_f32_16x16x32_bf16(a, b, c, 0, 0, 0)

// ---------------- K1: all casts/chunking + out init (5316 blocks) ----------
__global__ void k_prep(const float* __restrict__ token,
                       const float* __restrict__ label,
                       const float* __restrict__ b2,
                       const float* __restrict__ Wt,
                       const float* __restrict__ Wl,
                       const float* __restrict__ W1,
                       unsigned short* __restrict__ TC,
                       unsigned short* __restrict__ LC,
                       float* __restrict__ out,
                       unsigned short* __restrict__ WtC,
                       unsigned short* __restrict__ WlC,
                       unsigned short* __restrict__ W1C) {
  __shared__ float tile[64][33];
  const int bid = blockIdx.x;
  const int tid = threadIdx.x;
  if (bid < 408) {
    const float* in;
    unsigned short* o;
    int R, RP, kt, rt;
    if (bid < 384) {
      in = token; o = TC; R = 1024; RP = 1024; kt = bid % 24; rt = bid / 24;
    } else {
      in = label; o = LC; R = 50; RP = 64; kt = bid - 384; rt = 0;
    }
    const int k0 = kt * 32, r0 = rt * 64;
    const int tx = tid & 31, ty = tid >> 5;
#pragma unroll
    for (int i = 0; i < 8; i++) {
      int r = r0 + ty + i * 8;
      tile[ty + i * 8][tx] = in[(size_t)min(r, R - 1) * HH + k0 + tx];
    }
    __syncthreads();
    const int rl = tid & 63, kcl = tid >> 6;
    bf16x8 ov;
#pragma unroll
    for (int j = 0; j < 8; j++) ov[j] = (short)f2bf(tile[rl][kcl * 8 + j]);
    *(bf16x8*)&o[((size_t)((k0 >> 3) + kcl) * RP + r0 + rl) * 8] = ov;
  } else if (bid < 708) {
    int i = (bid - 408) * 256 + tid;
    if (i < BB * SS * CC * 3) out[i] = b2[i % 3];
  } else {
    const int wb = bid - 708;
    const float* in;
    unsigned short* o;
    int N, bx, by;
    if (wb < 3456) {
      in = W1; o = W1C; N = H4; bx = wb % 48; by = wb / 48;
    } else if (wb < 4032) {
      int b = wb - 3456; in = Wt; o = WtC; N = H2; bx = b % 24; by = b / 24;
    } else {
      int b = wb - 4032; in = Wl; o = WlC; N = H2; bx = b % 24; by = b / 24;
    }
    const int f = bx * 64 + (tid & 63);
    const int hc = by * 4 + (tid >> 6);
    bf16x8 ov;
#pragma unroll
    for (int j = 0; j < 8; j++)
      ov[j] = (short)f2bf(in[(size_t)(hc * 8 + j) * N + f]);
    *(bf16x8*)&o[((size_t)hc * N + f) * 8] = ov;
  }
}

// ---------------- shared K-loop: 128x128 tile, K=768, chunked operands -----
DEVINL void mm_kloop(const unsigned short* __restrict__ Ab, int NRA, int MA,
                     int m0, const unsigned short* __restrict__ Bt, int NRB,
                     int n0, unsigned short* As, unsigned short* Bs,
                     f32x4 (&acc)[4][4]) {
  const int tid = threadIdx.x;
  const int lane = tid & 63;
  const int wave = tid >> 6;
  const int q = lane >> 4;
  const int li = lane & 15;
  const int wm = (wave >> 1) * 64;
  const int wn = (wave & 1) * 64;

  int sr[4], skc[4], sra[4];
#pragma unroll
  for (int j = 0; j < 4; j++) {
    int slot = j * 256 + tid;
    skc[j] = slot >> 7;
    sr[j] = slot & 127;
    sra[j] = min(m0 + sr[j], MA - 1);
  }
  auto stage = [&](int kciter) {
#pragma unroll
    for (int j = 0; j < 4; j++) {
      int slot = j * 256 + tid;
      async16(Ab + ((size_t)(kciter + skc[j]) * NRA + sra[j]) * 8,
              (char*)As + slot * 16);
      async16(Bt + ((size_t)(kciter + skc[j]) * NRB + n0 + sr[j]) * 8,
              (char*)Bs + slot * 16);
    }
  };

  stage(0);
  for (int it = 0; it < 12; it++) {
    __syncthreads();  // stage landed
#pragma unroll
    for (int ks = 0; ks < 2; ks++) {
      bf16x8 af[4], bb[4];
#pragma unroll
      for (int mi = 0; mi < 4; mi++)
        af[mi] = *(const bf16x8*)&As[((ks * 4 + q) * 128 + wm + mi * 16 + li) * 8];
#pragma unroll
      for (int ni = 0; ni < 4; ni++)
        bb[ni] = *(const bf16x8*)&Bs[((ks * 4 + q) * 128 + wn + ni * 16 + li) * 8];
#pragma unroll
      for (int mi = 0; mi < 4; mi++)
#pragma unroll
        for (int ni = 0; ni < 4; ni++)
          acc[mi][ni] = MFMA16(af[mi], bb[ni], acc[mi][ni]);
    }
    __syncthreads();  // all reads done
    if (it + 1 < 12) stage((it + 1) * 8);
  }
}

// ---------------- K2: G1+G2 fused (108 blocks) ----------------
__global__ __launch_bounds__(256, 4) void k_mm1(
    const unsigned short* __restrict__ TC, const unsigned short* __restrict__ LC,
    const unsigned short* __restrict__ WtC, const unsigned short* __restrict__ WlC,
    const float* __restrict__ bt, const float* __restrict__ bl,
    unsigned short* __restrict__ TP, unsigned short* __restrict__ LP) {
  __shared__ __align__(16) unsigned short As[8 * 128 * 8];
  __shared__ __align__(16) unsigned short Bs[8 * 128 * 8];
  const int bid = blockIdx.x;
  const int nt = bid % 12, my = bid / 12;
  const bool tok = my < 8;
  const unsigned short* A = tok ? TC : LC;
  const unsigned short* Bt = tok ? WtC : WlC;
  const float* bias = tok ? bt : bl;
  unsigned short* C = tok ? TP : LP;
  const int NRA = tok ? 1024 : 64, MA = tok ? 1024 : 50;
  const int m0 = tok ? my * 128 : 0;
  const int ldc = NRA;
  const int n0 = nt * 128;

  f32x4 acc[4][4];
#pragma unroll
  for (int i = 0; i < 4; i++)
#pragma unroll
    for (int j = 0; j < 4; j++) acc[i][j] = (f32x4){0.f, 0.f, 0.f, 0.f};
  mm_kloop(A, NRA, MA, m0, Bt, H2, n0, As, Bs, acc);

  const int lane = threadIdx.x & 63, wave = threadIdx.x >> 6;
  const int q = lane >> 4, li = lane & 15;
  const int wm = (wave >> 1) * 64, wn = (wave & 1) * 64;
#pragma unroll
  for (int mi = 0; mi < 4; mi++)
#pragma unroll
    for (int rr = 0; rr < 4; rr++) {
      int row = m0 + wm + mi * 16 + q * 4 + rr;
      if (row < MA) {
#pragma unroll
        for (int ni = 0; ni < 4; ni++) {
          int col = n0 + wn + ni * 16 + li;
          C[((size_t)(col >> 3) * ldc + row) * 8 + (col & 7)] =
              f2bf(acc[mi][ni][rr] + bias[col]);
        }
      }
    }
}

// ---------------- K3: G3+G4 (216 blocks) + make_x (9600 blocks) ----------------
__global__ __launch_bounds__(256, 4) void k_mm2(
    const unsigned short* __restrict__ TP, const unsigned short* __restrict__ LP,
    const unsigned short* __restrict__ W1C,
    float* __restrict__ base, float* __restrict__ al,
    unsigned short* __restrict__ XC) {
  __shared__ __align__(16) unsigned short As[8 * 128 * 8];
  __shared__ __align__(16) unsigned short Bs[8 * 128 * 8];
  const int bid = blockIdx.x;
  if (bid < 216) {
    const int nt = bid % 24, my = bid / 24;
    const bool tok = my < 8;
    const unsigned short* A = tok ? TP : LP;
    const unsigned short* Bt = tok ? W1C : W1C + (size_t)96 * H4 * 8;
    float* Cf = tok ? base : al;
    const int NRA = tok ? 1024 : 64, MA = tok ? 1024 : 50;
    const int m0 = tok ? my * 128 : 0;
    const int n0 = nt * 128;

    f32x4 acc[4][4];
#pragma unroll
    for (int i = 0; i < 4; i++)
#pragma unroll
      for (int j = 0; j < 4; j++) acc[i][j] = (f32x4){0.f, 0.f, 0.f, 0.f};
    mm_kloop(A, NRA, MA, m0, Bt, H4, n0, As, Bs, acc);

    const int lane = threadIdx.x & 63, wave = threadIdx.x >> 6;
    const int q = lane >> 4, li = lane & 15;
    const int wm = (wave >> 1) * 64, wn = (wave & 1) * 64;
#pragma unroll
    for (int mi = 0; mi < 4; mi++)
#pragma unroll
      for (int rr = 0; rr < 4; rr++) {
        int row = m0 + wm + mi * 16 + q * 4 + rr;
        if (row < MA) {
#pragma unroll
          for (int ni = 0; ni < 4; ni++) {
            int col = n0 + wn + ni * 16 + li;
            Cf[(size_t)row * H4 + col] = acc[mi][ni][rr];
          }
        }
      }
  } else {
    // make_x: XC[bc][hc][s][8] = tb_chunk(96+hc)[b*512+s] * lb_chunk(96+hc)[bc]
    const int i = bid - 216;           // 0..9599
    const int bc = i / 192;
    const int rem = i % 192;
    const int hc = rem >> 1;
    const int s = (rem & 1) * 256 + threadIdx.x;
    const int b = bc / CC;
    bf16x8 tv = *(const bf16x8*)&TP[((size_t)(96 + hc) * 1024 + b * 512 + s) * 8];
    bf16x8 lv = *(const bf16x8*)&LP[((size_t)(96 + hc) * 64 + bc) * 8];
    bf16x8 o;
#pragma unroll
    for (int j = 0; j < 8; j++)
      o[j] = (short)f2bf(bf2f((unsigned short)tv[j]) * bf2f((unsigned short)lv[j]));
    *(bf16x8*)&XC[(size_t)bc * XC_STRIDE + ((size_t)hc * 512 + s) * 8] = o;
  }
}

// ---------------- K4: G5 scorer, 256x256 4-phase/tile schedule -------------
// grid 12 x 100, 512 threads = 8 waves (2M x 4N); wave tile 128x64, acc[8][4].
// BK=64 (8 kc), 12 K-tiles, double-buffered (128 KB LDS).
// Phases are STRAIGHT-LINE code (no lambdas over register arrays — R2's
// lambda capture-by-ref of af/bb defeated SROA and spilled to scratch:
// WRITE_SIZE 48->149 MB). Counted vmcnt: outstanding per thread cycles
// 4 -> 6 -> 8 -> wait(4); drains to 0 only in the last tile.

#define STAGE_A(T, H) do {                                                   \
    const int kcb_ = (T) * 8 + (H) * 4;                                      \
    char* dst_ = (char*)&As[(T) & 1][(H) * 4 * 256 * 8];                     \
    _Pragma("unroll")                                                        \
    for (int j_ = 0; j_ < 2; j_++) {                                         \
      int slot_ = j_ * 512 + tid;                                            \
      async16(Ab + ((size_t)(kcb_ + (slot_ >> 8)) * 512 + m0 + (slot_ & 255)) * 8, \
              dst_ + slot_ * 16);                                            \
    } } while (0)

#define STAGE_B(T, H) do {                                                   \
    const int kcb_ = (T) * 8 + (H) * 4;                                      \
    char* dst_ = (char*)&Bs[(T) & 1][(H) * 4 * 256 * 8];                     \
    _Pragma("unroll")                                                        \
    for (int j_ = 0; j_ < 2; j_++) {                                         \
      int slot_ = j_ * 512 + tid;                                            \
      async16(Bt + ((size_t)(kcb_ + (slot_ >> 8)) * 3072 + n0 + (slot_ & 255)) * 8, \
              dst_ + slot_ * 16);                                            \
    } } while (0)

__global__ __launch_bounds__(512, 2) void k_scorer(
    const unsigned short* __restrict__ XC,   // per-bc slabs [96][512][8]
    const unsigned short* __restrict__ Bt,   // W1p chunked [96][3072][8]
    const float* __restrict__ base, const float* __restrict__ al,
    const float* __restrict__ b1, const float* __restrict__ W2,
    float* __restrict__ out) {
  __shared__ __align__(16) unsigned short As[2][8 * 256 * 8];  // 2 x 32 KB
  __shared__ __align__(16) unsigned short Bs[2][8 * 256 * 8];  // 2 x 32 KB
  const int tid = threadIdx.x;
  const int lane = tid & 63;
  const int wave = tid >> 6;
  const int q = lane >> 4;
  const int li = lane & 15;
  const int wm = (wave >> 2) * 128;        // 2 waves in M
  const int wn = (wave & 3) * 64;          // 4 waves in N

  const int n0 = blockIdx.x * 256;
  const int bc = blockIdx.y >> 1;
  const int m0 = (blockIdx.y & 1) * 256;
  const unsigned short* Ab = XC + (size_t)bc * XC_STRIDE;

  f32x4 acc[8][4];
#pragma unroll
  for (int i = 0; i < 8; i++)
#pragma unroll
    for (int j = 0; j < 4; j++) acc[i][j] = (f32x4){0.f, 0.f, 0.f, 0.f};

  // prologue: tile 0's four half-tiles in flight; drain first K-half only
  STAGE_A(0, 0); STAGE_B(0, 0); STAGE_A(0, 1); STAGE_B(0, 1);
  asm volatile("s_waitcnt vmcnt(4)" ::: "memory");
  BAR();

#pragma unroll 1
  for (int t = 0; t < 12; t++) {
    const unsigned short* Ad = &As[t & 1][0];
    const unsigned short* Bd = &Bs[t & 1][0];
    const bool iss = (t < 11);
    bf16x8 af[8], bb[4];

    // ---- ph0: ks=0, nh=0 (A-h0/B-h0 landed at previous boundary)
#pragma unroll
    for (int mi = 0; mi < 8; mi++)
      af[mi] = *(const bf16x8*)&Ad[((0 + q) * 256 + wm + mi * 16 + li) * 8];
    bb[0] = *(const bf16x8*)&Bd[((0 + q) * 256 + wn + 0 * 16 + li) * 8];
    bb[1] = *(const bf16x8*)&Bd[((0 + q) * 256 + wn + 1 * 16 + li) * 8];
    if (iss) STAGE_A(t + 1, 0);
    BAR();
    __builtin_amdgcn_s_setprio(1);
#pragma unroll
    for (int mi = 0; mi < 8; mi++) {
      acc[mi][0] = MFMA16(af[mi], bb[0], acc[mi][0]);
      acc[mi][1] = MFMA16(af[mi], bb[1], acc[mi][1]);
    }
    __builtin_amdgcn_s_setprio(0);
    BAR();

    // ---- ph1: ks=0, nh=1
    bb[2] = *(const bf16x8*)&Bd[((0 + q) * 256 + wn + 2 * 16 + li) * 8];
    bb[3] = *(const bf16x8*)&Bd[((0 + q) * 256 + wn + 3 * 16 + li) * 8];
    if (iss) STAGE_B(t + 1, 0);
    BAR();
    __builtin_amdgcn_s_setprio(1);
#pragma unroll
    for (int mi = 0; mi < 8; mi++) {
      acc[mi][2] = MFMA16(af[mi], bb[2], acc[mi][2]);
      acc[mi][3] = MFMA16(af[mi], bb[3], acc[mi][3]);
    }
    __builtin_amdgcn_s_setprio(0);
    if (iss) { asm volatile("s_waitcnt vmcnt(4)" ::: "memory"); }
    else     { asm volatile("s_waitcnt vmcnt(0)" ::: "memory"); }
    BAR();

    // ---- ph2: ks=1, nh=0 (A-h1/B-h1 just drained by all waves)
#pragma unroll
    for (int mi = 0; mi < 8; mi++)
      af[mi] = *(const bf16x8*)&Ad[((4 + q) * 256 + wm + mi * 16 + li) * 8];
    bb[0] = *(const bf16x8*)&Bd[((4 + q) * 256 + wn + 0 * 16 + li) * 8];
    bb[1] = *(const bf16x8*)&Bd[((4 + q) * 256 + wn + 1 * 16 + li) * 8];
    if (iss) STAGE_A(t + 1, 1);
    BAR();
    __builtin_amdgcn_s_setprio(1);
#pragma unroll
    for (int mi = 0; mi < 8; mi++) {
      acc[mi][0] = MFMA16(af[mi], bb[0], acc[mi][0]);
      acc[mi][1] = MFMA16(af[mi], bb[1], acc[mi][1]);
    }
    __builtin_amdgcn_s_setprio(0);
    BAR();

    // ---- ph3: ks=1, nh=1
    bb[2] = *(const bf16x8*)&Bd[((4 + q) * 256 + wn + 2 * 16 + li) * 8];
    bb[3] = *(const bf16x8*)&Bd[((4 + q) * 256 + wn + 3 * 16 + li) * 8];
    if (iss) STAGE_B(t + 1, 1);
    BAR();
    __builtin_amdgcn_s_setprio(1);
#pragma unroll
    for (int mi = 0; mi < 8; mi++) {
      acc[mi][2] = MFMA16(af[mi], bb[2], acc[mi][2]);
      acc[mi][3] = MFMA16(af[mi], bb[3], acc[mi][3]);
    }
    __builtin_amdgcn_s_setprio(0);
    if (iss) { asm volatile("s_waitcnt vmcnt(4)" ::: "memory"); }
    else     { asm volatile("s_waitcnt vmcnt(0)" ::: "memory"); }
    BAR();
  }

  // epilogue: E = acc + base + al + b1; relu; out += E @ W2 via MFMA.
  // Scratch in As[0] (last tile read only buffers [1] — disjoint; all waves
  // passed the final barrier).
  const int b = bc / CC, c = bc % CC;
  int fcol[4];
  float alb[4];
#pragma unroll
  for (int ni = 0; ni < 4; ni++) {
    int f = n0 + wn + ni * 16 + li;
    fcol[ni] = f;
    alb[ni] = al[(size_t)bc * H4 + f] + b1[f];
  }
  bf16x8 w2f[2];
#pragma unroll
  for (int ks = 0; ks < 2; ks++)
#pragma unroll
    for (int jj = 0; jj < 8; jj++) {
      int f = n0 + wn + ks * 32 + q * 8 + jj;
      float v = (li < 3) ? W2[(size_t)f * 3 + li] : 0.f;
      w2f[ks][jj] = (short)f2bf(v);
    }
  unsigned short* Ew = &As[0][0] + wave * 1152;  // 2304 B per wave

#pragma unroll
  for (int mi = 0; mi < 8; mi++) {
    float bsv[4][4];
#pragma unroll
    for (int rr = 0; rr < 4; rr++) {
      int s_l = m0 + wm + mi * 16 + q * 4 + rr;
      const float* bp = base + (size_t)(b * SS + s_l) * H4;
#pragma unroll
      for (int ni = 0; ni < 4; ni++) bsv[ni][rr] = bp[fcol[ni]];
    }
#pragma unroll
    for (int rr = 0; rr < 4; rr++)
#pragma unroll
      for (int ni = 0; ni < 4; ni++) {
        float v = acc[mi][ni][rr] + bsv[ni][rr] + alb[ni];
        v = fmaxf(v, 0.f);
        Ew[(q * 4 + rr) * 72 + ni * 16 + li] = f2bf(v);
      }
    f32x4 oc = (f32x4){0.f, 0.f, 0.f, 0.f};
#pragma unroll
    for (int ks = 0; ks < 2; ks++) {
      bf16x8 ef = *(const bf16x8*)&Ew[li * 72 + ks * 32 + q * 8];
      oc = MFMA16(ef, w2f[ks], oc);
    }
#pragma unroll
    for (int rr = 0; rr < 4; rr++) {
      int s_l = m0 + wm + mi * 16 + q * 4 + rr;
      if (li < 3)
        atomicAdd(&out[((size_t)(b * SS + s_l) * CC + c) * 3 + li], oc[rr]);
    }
  }
}

// ---------------- host launch ----------------

extern "C" void kernel_launch(void* const* d_in, const int* in_sizes, int n_in,
                              void* d_out, int out_size, void* d_ws, size_t ws_size,
                              hipStream_t stream) {
  (void)in_sizes; (void)n_in; (void)ws_size; (void)out_size;
  const float* token = (const float*)d_in[0];
  const float* label = (const float*)d_in[1];
  const float* Wt    = (const float*)d_in[2];
  const float* bt    = (const float*)d_in[3];
  const float* Wl    = (const float*)d_in[4];
  const float* bl    = (const float*)d_in[5];
  const float* W1    = (const float*)d_in[6];
  const float* b1    = (const float*)d_in[7];
  const float* W2    = (const float*)d_in[8];
  const float* b2    = (const float*)d_in[9];
  float* out = (float*)d_out;

  char* p = (char*)d_ws;
  auto alloc = [&](size_t bytes) {
    char* r = p;
    p += (bytes + 255) & ~(size_t)255;
    return r;
  };
  unsigned short* TC  = (unsigned short*)alloc((size_t)96 * 1024 * 8 * 2);
  unsigned short* LC  = (unsigned short*)alloc((size_t)96 * 64 * 8 * 2);
  unsigned short* WtC = (unsigned short*)alloc((size_t)96 * 1536 * 8 * 2);
  unsigned short* WlC = (unsigned short*)alloc((size_t)96 * 1536 * 8 * 2);
  unsigned short* W1C = (unsigned short*)alloc((size_t)288 * 3072 * 8 * 2);
  unsigned short* TP  = (unsigned short*)alloc((size_t)192 * 1024 * 8 * 2);
  unsigned short* LP  = (unsigned short*)alloc((size_t)192 * 64 * 8 * 2);
  unsigned short* XC  = (unsigned short*)alloc((size_t)CC * BB * XC_STRIDE * 2);
  float* base = (float*)alloc((size_t)BB * SS * H4 * 4);
  float* al   = (float*)alloc((size_t)BB * CC * H4 * 4);

  // K1: all casts/chunking + out init
  k_prep<<<5316, 256, 0, stream>>>(token, label, b2, Wt, Wl, W1,
                                   TC, LC, out, WtC, WlC, W1C);
  // K2: G1+G2 fused projections
  k_mm1<<<108, 256, 0, stream>>>(TC, LC, WtC, WlC, bt, bl, TP, LP);
  // K3: G3+G4 GEMMs + make_x
  k_mm2<<<9816, 256, 0, stream>>>(TP, LP, W1C, base, al, XC);
  // K4: G5 scorer, 256x256 4-phase/tile
  k_scorer<<<dim3(12, 100), 512, 0, stream>>>(
      XC, W1C + (size_t)192 * H4 * 8, base, al, b1, W2, out);
}

// Round 5
// 281.524 us; speedup vs baseline: 1.5960x; 1.0898x over previous
//
#include <hip/hip_runtime.h>
#include <hip/hip_bf16.h>
#include <cstdint>
#include <cstddef>

// Shapes: B=2, S=512, C=25, H=768, 2H=1536, 3H=2304, 4H=3072
#define BB 2
#define SS 512
#define CC 25
#define HH 768
#define H2 1536
#define H3 2304
#define H4 3072
// chunked layout: [kc][row][8] bf16, kc = k/8
#define XC_STRIDE ((size_t)96 * 512 * 8)   // per-bc X slab, 96 chunks x 512 rows

typedef __attribute__((ext_vector_type(8))) short bf16x8;
typedef __attribute__((ext_vector_type(4))) float f32x4;

#define DEVINL static __device__ __forceinline__

DEVINL unsigned short f2bf(float f) {
  union { float f; unsigned u; } v; v.f = f;
  unsigned r = v.u + 0x7FFF + ((v.u >> 16) & 1);  // RNE
  return (unsigned short)(r >> 16);
}
DEVINL float bf2f(unsigned short b) {
  union { unsigned u; float f; } v; v.u = ((unsigned)b) << 16; return v.f;
}

DEVINL void async16(const void* g, void* l) {
  __builtin_amdgcn_global_load_lds(
      (const __attribute__((address_space(1))) void*)g,
      (__attribute__((address_space(3))) void*)l, 16, 0, 0);
}

#define MFMA16(a, b, c) __builtin_amdgcn_mfma_f32_16x16x32_bf16(a, b, c, 0, 0, 0)

// ---------------- K1: all casts/chunking + out init (5316 blocks) ----------
__global__ void k_prep(const float* __restrict__ token,
                       const float* __restrict__ label,
                       const float* __restrict__ b2,
                       const float* __restrict__ Wt,
                       const float* __restrict__ Wl,
                       const float* __restrict__ W1,
                       unsigned short* __restrict__ TC,
                       unsigned short* __restrict__ LC,
                       float* __restrict__ out,
                       unsigned short* __restrict__ WtC,
                       unsigned short* __restrict__ WlC,
                       unsigned short* __restrict__ W1C) {
  __shared__ float tile[64][33];
  const int bid = blockIdx.x;
  const int tid = threadIdx.x;
  if (bid < 408) {
    const float* in;
    unsigned short* o;
    int R, RP, kt, rt;
    if (bid < 384) {
      in = token; o = TC; R = 1024; RP = 1024; kt = bid % 24; rt = bid / 24;
    } else {
      in = label; o = LC; R = 50; RP = 64; kt = bid - 384; rt = 0;
    }
    const int k0 = kt * 32, r0 = rt * 64;
    const int tx = tid & 31, ty = tid >> 5;
#pragma unroll
    for (int i = 0; i < 8; i++) {
      int r = r0 + ty + i * 8;
      tile[ty + i * 8][tx] = in[(size_t)min(r, R - 1) * HH + k0 + tx];
    }
    __syncthreads();
    const int rl = tid & 63, kcl = tid >> 6;
    bf16x8 ov;
#pragma unroll
    for (int j = 0; j < 8; j++) ov[j] = (short)f2bf(tile[rl][kcl * 8 + j]);
    *(bf16x8*)&o[((size_t)((k0 >> 3) + kcl) * RP + r0 + rl) * 8] = ov;
  } else if (bid < 708) {
    int i = (bid - 408) * 256 + tid;
    if (i < BB * SS * CC * 3) out[i] = b2[i % 3];
  } else {
    const int wb = bid - 708;
    const float* in;
    unsigned short* o;
    int N, bx, by;
    if (wb < 3456) {
      in = W1; o = W1C; N = H4; bx = wb % 48; by = wb / 48;
    } else if (wb < 4032) {
      int b = wb - 3456; in = Wt; o = WtC; N = H2; bx = b % 24; by = b / 24;
    } else {
      int b = wb - 4032; in = Wl; o = WlC; N = H2; bx = b % 24; by = b / 24;
    }
    const int f = bx * 64 + (tid & 63);
    const int hc = by * 4 + (tid >> 6);
    bf16x8 ov;
#pragma unroll
    for (int j = 0; j < 8; j++)
      ov[j] = (short)f2bf(in[(size_t)(hc * 8 + j) * N + f]);
    *(bf16x8*)&o[((size_t)hc * N + f) * 8] = ov;
  }
}

// ---------------- shared K-loop: 128x128 tile, K=768, chunked operands -----
DEVINL void mm_kloop(const unsigned short* __restrict__ Ab, int NRA, int MA,
                     int m0, const unsigned short* __restrict__ Bt, int NRB,
                     int n0, unsigned short* As, unsigned short* Bs,
                     f32x4 (&acc)[4][4]) {
  const int tid = threadIdx.x;
  const int lane = tid & 63;
  const int wave = tid >> 6;
  const int q = lane >> 4;
  const int li = lane & 15;
  const int wm = (wave >> 1) * 64;
  const int wn = (wave & 1) * 64;

  int sr[4], skc[4], sra[4];
#pragma unroll
  for (int j = 0; j < 4; j++) {
    int slot = j * 256 + tid;
    skc[j] = slot >> 7;
    sr[j] = slot & 127;
    sra[j] = min(m0 + sr[j], MA - 1);
  }
  auto stage = [&](int kciter) {
#pragma unroll
    for (int j = 0; j < 4; j++) {
      int slot = j * 256 + tid;
      async16(Ab + ((size_t)(kciter + skc[j]) * NRA + sra[j]) * 8,
              (char*)As + slot * 16);
      async16(Bt + ((size_t)(kciter + skc[j]) * NRB + n0 + sr[j]) * 8,
              (char*)Bs + slot * 16);
    }
  };

  stage(0);
  for (int it = 0; it < 12; it++) {
    __syncthreads();  // stage landed
#pragma unroll
    for (int ks = 0; ks < 2; ks++) {
      bf16x8 af[4], bb[4];
#pragma unroll
      for (int mi = 0; mi < 4; mi++)
        af[mi] = *(const bf16x8*)&As[((ks * 4 + q) * 128 + wm + mi * 16 + li) * 8];
#pragma unroll
      for (int ni = 0; ni < 4; ni++)
        bb[ni] = *(const bf16x8*)&Bs[((ks * 4 + q) * 128 + wn + ni * 16 + li) * 8];
#pragma unroll
      for (int mi = 0; mi < 4; mi++)
#pragma unroll
        for (int ni = 0; ni < 4; ni++)
          acc[mi][ni] = MFMA16(af[mi], bb[ni], acc[mi][ni]);
    }
    __syncthreads();  // all reads done
    if (it + 1 < 12) stage((it + 1) * 8);
  }
}

// ---------------- K2: G1+G2 fused (108 blocks) ----------------
__global__ __launch_bounds__(256, 4) void k_mm1(
    const unsigned short* __restrict__ TC, const unsigned short* __restrict__ LC,
    const unsigned short* __restrict__ WtC, const unsigned short* __restrict__ WlC,
    const float* __restrict__ bt, const float* __restrict__ bl,
    unsigned short* __restrict__ TP, unsigned short* __restrict__ LP) {
  __shared__ __align__(16) unsigned short As[8 * 128 * 8];
  __shared__ __align__(16) unsigned short Bs[8 * 128 * 8];
  const int bid = blockIdx.x;
  const int nt = bid % 12, my = bid / 12;
  const bool tok = my < 8;
  const unsigned short* A = tok ? TC : LC;
  const unsigned short* Bt = tok ? WtC : WlC;
  const float* bias = tok ? bt : bl;
  unsigned short* C = tok ? TP : LP;
  const int NRA = tok ? 1024 : 64, MA = tok ? 1024 : 50;
  const int m0 = tok ? my * 128 : 0;
  const int ldc = NRA;
  const int n0 = nt * 128;

  f32x4 acc[4][4];
#pragma unroll
  for (int i = 0; i < 4; i++)
#pragma unroll
    for (int j = 0; j < 4; j++) acc[i][j] = (f32x4){0.f, 0.f, 0.f, 0.f};
  mm_kloop(A, NRA, MA, m0, Bt, H2, n0, As, Bs, acc);

  const int lane = threadIdx.x & 63, wave = threadIdx.x >> 6;
  const int q = lane >> 4, li = lane & 15;
  const int wm = (wave >> 1) * 64, wn = (wave & 1) * 64;
#pragma unroll
  for (int mi = 0; mi < 4; mi++)
#pragma unroll
    for (int rr = 0; rr < 4; rr++) {
      int row = m0 + wm + mi * 16 + q * 4 + rr;
      if (row < MA) {
#pragma unroll
        for (int ni = 0; ni < 4; ni++) {
          int col = n0 + wn + ni * 16 + li;
          C[((size_t)(col >> 3) * ldc + row) * 8 + (col & 7)] =
              f2bf(acc[mi][ni][rr] + bias[col]);
        }
      }
    }
}

// ---------------- K3: G3+G4 (216 blocks) + make_x (9600 blocks) ----------------
__global__ __launch_bounds__(256, 4) void k_mm2(
    const unsigned short* __restrict__ TP, const unsigned short* __restrict__ LP,
    const unsigned short* __restrict__ W1C,
    float* __restrict__ base, float* __restrict__ al,
    unsigned short* __restrict__ XC) {
  __shared__ __align__(16) unsigned short As[8 * 128 * 8];
  __shared__ __align__(16) unsigned short Bs[8 * 128 * 8];
  const int bid = blockIdx.x;
  if (bid < 216) {
    const int nt = bid % 24, my = bid / 24;
    const bool tok = my < 8;
    const unsigned short* A = tok ? TP : LP;
    const unsigned short* Bt = tok ? W1C : W1C + (size_t)96 * H4 * 8;
    float* Cf = tok ? base : al;
    const int NRA = tok ? 1024 : 64, MA = tok ? 1024 : 50;
    const int m0 = tok ? my * 128 : 0;
    const int n0 = nt * 128;

    f32x4 acc[4][4];
#pragma unroll
    for (int i = 0; i < 4; i++)
#pragma unroll
      for (int j = 0; j < 4; j++) acc[i][j] = (f32x4){0.f, 0.f, 0.f, 0.f};
    mm_kloop(A, NRA, MA, m0, Bt, H4, n0, As, Bs, acc);

    const int lane = threadIdx.x & 63, wave = threadIdx.x >> 6;
    const int q = lane >> 4, li = lane & 15;
    const int wm = (wave >> 1) * 64, wn = (wave & 1) * 64;
#pragma unroll
    for (int mi = 0; mi < 4; mi++)
#pragma unroll
      for (int rr = 0; rr < 4; rr++) {
        int row = m0 + wm + mi * 16 + q * 4 + rr;
        if (row < MA) {
#pragma unroll
          for (int ni = 0; ni < 4; ni++) {
            int col = n0 + wn + ni * 16 + li;
            Cf[(size_t)row * H4 + col] = acc[mi][ni][rr];
          }
        }
      }
  } else {
    // make_x: XC[bc][hc][s][8] = tb_chunk(96+hc)[b*512+s] * lb_chunk(96+hc)[bc]
    const int i = bid - 216;           // 0..9599
    const int bc = i / 192;
    const int rem = i % 192;
    const int hc = rem >> 1;
    const int s = (rem & 1) * 256 + threadIdx.x;
    const int b = bc / CC;
    bf16x8 tv = *(const bf16x8*)&TP[((size_t)(96 + hc) * 1024 + b * 512 + s) * 8];
    bf16x8 lv = *(const bf16x8*)&LP[((size_t)(96 + hc) * 64 + bc) * 8];
    bf16x8 o;
#pragma unroll
    for (int j = 0; j < 8; j++)
      o[j] = (short)f2bf(bf2f((unsigned short)tv[j]) * bf2f((unsigned short)lv[j]));
    *(bf16x8*)&XC[(size_t)bc * XC_STRIDE + ((size_t)hc * 512 + s) * 8] = o;
  }
}

// ---------------- K4: G5 scorer (grid 24 x 200) ----------------
// R0 structure, but A-fragments load DIRECTLY global->register (the chunked
// XC layout makes a fragment one contiguous 16B/lane load: 4x256B coalesced
// segments per wave), ping-pong prefetched one K-step ahead so L2 latency
// hides under the current step's LDS reads + MFMAs. Only B is LDS-staged
// (shared across the 2 M-waves). Halves async16 count, halves LDS traffic
// (LDS 32->16 KB), removes half the staging VALU.
// __launch_bounds__(256,3): allocator budget ~170 VGPR — never force-spill
// (R2 lesson); if actual usage <=128 HW still runs 4 blocks/CU.

#define STAGE_B4(KC0) do {                                                    \
    _Pragma("unroll")                                                         \
    for (int j_ = 0; j_ < 4; j_++) {                                          \
      int slot_ = j_ * 256 + tid;                                             \
      async16(Bt + ((size_t)((KC0) + (slot_ >> 7)) * H4 + n0 + (slot_ & 127)) * 8, \
              (char*)Bs + slot_ * 16);                                        \
    } } while (0)

__global__ __launch_bounds__(256, 3) void k_scorer(
    const unsigned short* __restrict__ XC,   // per-bc slabs [96][512][8]
    const unsigned short* __restrict__ Bt,   // W1p chunked [96][3072][8]
    const float* __restrict__ base, const float* __restrict__ al,
    const float* __restrict__ b1, const float* __restrict__ W2,
    float* __restrict__ out) {
  __shared__ __align__(16) unsigned short Bs[8 * 128 * 8];  // 16 KB
  const int tid = threadIdx.x;
  const int lane = tid & 63;
  const int wave = tid >> 6;
  const int q = lane >> 4;
  const int li = lane & 15;
  const int wm = (wave >> 1) * 64;
  const int wn = (wave & 1) * 64;

  const int n0 = blockIdx.x * 128;
  const int bc = blockIdx.y >> 2;
  const int m0 = (blockIdx.y & 3) * 128;
  const unsigned short* Ab = XC + (size_t)bc * XC_STRIDE;

  // per-mi A fragment base pointers (row part constant; add chunk*4096 elems)
  const unsigned short* ap[4];
#pragma unroll
  for (int mi = 0; mi < 4; mi++)
    ap[mi] = Ab + (size_t)(m0 + wm + mi * 16 + li) * 8;

  f32x4 acc[4][4];
#pragma unroll
  for (int i = 0; i < 4; i++)
#pragma unroll
    for (int j = 0; j < 4; j++) acc[i][j] = (f32x4){0.f, 0.f, 0.f, 0.f};

  // prologue: A fragments for steps 0,1 in flight; B tile 0 staging
  bf16x8 af0[4], af1[4];
#pragma unroll
  for (int mi = 0; mi < 4; mi++)
    af0[mi] = *(const bf16x8*)(ap[mi] + (size_t)(0 + q) * 4096);
#pragma unroll
  for (int mi = 0; mi < 4; mi++)
    af1[mi] = *(const bf16x8*)(ap[mi] + (size_t)(4 + q) * 4096);
  STAGE_B4(0);

#pragma unroll 1
  for (int it = 0; it < 12; it++) {
    __syncthreads();  // B landed (drains vmem — af prefetches also complete)
    bf16x8 bb[4];
    // ---- ks = 0: consume af0, prefetch af0 <- step 2*(it+1)
#pragma unroll
    for (int ni = 0; ni < 4; ni++)
      bb[ni] = *(const bf16x8*)&Bs[((0 + q) * 128 + wn + ni * 16 + li) * 8];
#pragma unroll
    for (int mi = 0; mi < 4; mi++)
#pragma unroll
      for (int ni = 0; ni < 4; ni++)
        acc[mi][ni] = MFMA16(af0[mi], bb[ni], acc[mi][ni]);
    {
      const int cb0 = (it < 11) ? (it + 1) * 8 : 88;  // clamp: keep addr valid
#pragma unroll
      for (int mi = 0; mi < 4; mi++)
        af0[mi] = *(const bf16x8*)(ap[mi] + (size_t)(cb0 + q) * 4096);
    }
    // ---- ks = 1: consume af1, prefetch af1 <- step 2*(it+1)+1
#pragma unroll
    for (int ni = 0; ni < 4; ni++)
      bb[ni] = *(const bf16x8*)&Bs[((4 + q) * 128 + wn + ni * 16 + li) * 8];
#pragma unroll
    for (int mi = 0; mi < 4; mi++)
#pragma unroll
      for (int ni = 0; ni < 4; ni++)
        acc[mi][ni] = MFMA16(af1[mi], bb[ni], acc[mi][ni]);
    {
      const int cb1 = (it < 11) ? (it + 1) * 8 + 4 : 92;
#pragma unroll
      for (int mi = 0; mi < 4; mi++)
        af1[mi] = *(const bf16x8*)(ap[mi] + (size_t)(cb1 + q) * 4096);
    }
    __syncthreads();  // all B reads done
    if (it < 11) STAGE_B4((it + 1) * 8);
  }

  // epilogue: E = acc + base + al + b1; relu; out += E @ W2 via MFMA
  const int b = bc / CC, c = bc % CC;
  int fcol[4];
  float alb[4];
#pragma unroll
  for (int ni = 0; ni < 4; ni++) {
    int f = n0 + wn + ni * 16 + li;
    fcol[ni] = f;
    alb[ni] = al[(size_t)bc * H4 + f] + b1[f];
  }
  bf16x8 w2f[2];
#pragma unroll
  for (int ks = 0; ks < 2; ks++)
#pragma unroll
    for (int jj = 0; jj < 8; jj++) {
      int f = n0 + wn + ks * 32 + q * 8 + jj;
      float v = (li < 3) ? W2[(size_t)f * 3 + li] : 0.f;
      w2f[ks][jj] = (short)f2bf(v);
    }
  unsigned short* Ew = (unsigned short*)((char*)Bs + wave * 2304);

#pragma unroll
  for (int mi = 0; mi < 4; mi++) {
    float bs[4][4];
#pragma unroll
    for (int rr = 0; rr < 4; rr++) {
      int s_l = m0 + wm + mi * 16 + q * 4 + rr;
      const float* bp = base + (size_t)(b * SS + s_l) * H4;
#pragma unroll
      for (int ni = 0; ni < 4; ni++) bs[ni][rr] = bp[fcol[ni]];
    }
#pragma unroll
    for (int rr = 0; rr < 4; rr++)
#pragma unroll
      for (int ni = 0; ni < 4; ni++) {
        float v = acc[mi][ni][rr] + bs[ni][rr] + alb[ni];
        v = fmaxf(v, 0.f);
        Ew[(q * 4 + rr) * 72 + ni * 16 + li] = f2bf(v);
      }
    f32x4 oc = (f32x4){0.f, 0.f, 0.f, 0.f};
#pragma unroll
    for (int ks = 0; ks < 2; ks++) {
      bf16x8 ef = *(const bf16x8*)&Ew[li * 72 + ks * 32 + q * 8];
      oc = MFMA16(ef, w2f[ks], oc);
    }
#pragma unroll
    for (int rr = 0; rr < 4; rr++) {
      int s_l = m0 + wm + mi * 16 + q * 4 + rr;
      if (li < 3)
        atomicAdd(&out[((size_t)(b * SS + s_l) * CC + c) * 3 + li], oc[rr]);
    }
  }
}

// ---------------- host launch ----------------

extern "C" void kernel_launch(void* const* d_in, const int* in_sizes, int n_in,
                              void* d_out, int out_size, void* d_ws, size_t ws_size,
                              hipStream_t stream) {
  (void)in_sizes; (void)n_in; (void)ws_size; (void)out_size;
  const float* token = (const float*)d_in[0];
  const float* label = (const float*)d_in[1];
  const float* Wt    = (const float*)d_in[2];
  const float* bt    = (const float*)d_in[3];
  const float* Wl    = (const float*)d_in[4];
  const float* bl    = (const float*)d_in[5];
  const float* W1    = (const float*)d_in[6];
  const float* b1    = (const float*)d_in[7];
  const float* W2    = (const float*)d_in[8];
  const float* b2    = (const float*)d_in[9];
  float* out = (float*)d_out;

  char* p = (char*)d_ws;
  auto alloc = [&](size_t bytes) {
    char* r = p;
    p += (bytes + 255) & ~(size_t)255;
    return r;
  };
  unsigned short* TC  = (unsigned short*)alloc((size_t)96 * 1024 * 8 * 2);
  unsigned short* LC  = (unsigned short*)alloc((size_t)96 * 64 * 8 * 2);
  unsigned short* WtC = (unsigned short*)alloc((size_t)96 * 1536 * 8 * 2);
  unsigned short* WlC = (unsigned short*)alloc((size_t)96 * 1536 * 8 * 2);
  unsigned short* W1C = (unsigned short*)alloc((size_t)288 * 3072 * 8 * 2);
  unsigned short* TP  = (unsigned short*)alloc((size_t)192 * 1024 * 8 * 2);
  unsigned short* LP  = (unsigned short*)alloc((size_t)192 * 64 * 8 * 2);
  unsigned short* XC  = (unsigned short*)alloc((size_t)CC * BB * XC_STRIDE * 2);
  float* base = (float*)alloc((size_t)BB * SS * H4 * 4);
  float* al   = (float*)alloc((size_t)BB * CC * H4 * 4);

  // K1: all casts/chunking + out init
  k_prep<<<5316, 256, 0, stream>>>(token, label, b2, Wt, Wl, W1,
                                   TC, LC, out, WtC, WlC, W1C);
  // K2: G1+G2 fused projections
  k_mm1<<<108, 256, 0, stream>>>(TC, LC, WtC, WlC, bt, bl, TP, LP);
  // K3: G3+G4 GEMMs + make_x
  k_mm2<<<9816, 256, 0, stream>>>(TP, LP, W1C, base, al, XC);
  // K4: G5 scorer (A direct-to-register, B LDS-staged)
  k_scorer<<<dim3(24, 200), 256, 0, stream>>>(
      XC, W1C + (size_t)192 * H4 * 8, base, al, b1, W2, out);
}

// Round 6
// 273.490 us; speedup vs baseline: 1.6428x; 1.0294x over previous
//
#include <hip/hip_runtime.h>
#include <hip/hip_bf16.h>
#include <cstdint>
#include <cstddef>

// Shapes: B=2, S=512, C=25, H=768, 2H=1536, 3H=2304, 4H=3072
#define BB 2
#define SS 512
#define CC 25
#define HH 768
#define H2 1536
#define H3 2304
#define H4 3072
// chunked layout: [kc][row][8] bf16, kc = k/8
#define XC_STRIDE ((size_t)96 * 512 * 8)   // per-bc X slab, 96 chunks x 512 rows

typedef __attribute__((ext_vector_type(8))) short bf16x8;
typedef __attribute__((ext_vector_type(4))) float f32x4;

#define DEVINL static __device__ __forceinline__

DEVINL unsigned short f2bf(float f) {
  union { float f; unsigned u; } v; v.f = f;
  unsigned r = v.u + 0x7FFF + ((v.u >> 16) & 1);  // RNE
  return (unsigned short)(r >> 16);
}
DEVINL float bf2f(unsigned short b) {
  union { unsigned u; float f; } v; v.u = ((unsigned)b) << 16; return v.f;
}

DEVINL void async16(const void* g, void* l) {
  __builtin_amdgcn_global_load_lds(
      (const __attribute__((address_space(1))) void*)g,
      (__attribute__((address_space(3))) void*)l, 16, 0, 0);
}

// raw barrier (no implicit waitcnt drain) with compiler reorder fence
#define BAR() do { asm volatile("" ::: "memory"); \
                   __builtin_amdgcn_s_barrier();  \
                   asm volatile("" ::: "memory"); } while (0)
#define MFMA16(a, b, c) __builtin_amdgcn_mfma_f32_16x16x32_bf16(a, b, c, 0, 0, 0)

// ---------------- K1: all casts/chunking + out init (5316 blocks) ----------
__global__ void k_prep(const float* __restrict__ token,
                       const float* __restrict__ label,
                       const float* __restrict__ b2,
                       const float* __restrict__ Wt,
                       const float* __restrict__ Wl,
                       const float* __restrict__ W1,
                       unsigned short* __restrict__ TC,
                       unsigned short* __restrict__ LC,
                       float* __restrict__ out,
                       unsigned short* __restrict__ WtC,
                       unsigned short* __restrict__ WlC,
                       unsigned short* __restrict__ W1C) {
  __shared__ float tile[64][33];
  const int bid = blockIdx.x;
  const int tid = threadIdx.x;
  if (bid < 408) {
    const float* in;
    unsigned short* o;
    int R, RP, kt, rt;
    if (bid < 384) {
      in = token; o = TC; R = 1024; RP = 1024; kt = bid % 24; rt = bid / 24;
    } else {
      in = label; o = LC; R = 50; RP = 64; kt = bid - 384; rt = 0;
    }
    const int k0 = kt * 32, r0 = rt * 64;
    const int tx = tid & 31, ty = tid >> 5;
#pragma unroll
    for (int i = 0; i < 8; i++) {
      int r = r0 + ty + i * 8;
      tile[ty + i * 8][tx] = in[(size_t)min(r, R - 1) * HH + k0 + tx];
    }
    __syncthreads();
    const int rl = tid & 63, kcl = tid >> 6;
    bf16x8 ov;
#pragma unroll
    for (int j = 0; j < 8; j++) ov[j] = (short)f2bf(tile[rl][kcl * 8 + j]);
    *(bf16x8*)&o[((size_t)((k0 >> 3) + kcl) * RP + r0 + rl) * 8] = ov;
  } else if (bid < 708) {
    int i = (bid - 408) * 256 + tid;
    if (i < BB * SS * CC * 3) out[i] = b2[i % 3];
  } else {
    const int wb = bid - 708;
    const float* in;
    unsigned short* o;
    int N, bx, by;
    if (wb < 3456) {
      in = W1; o = W1C; N = H4; bx = wb % 48; by = wb / 48;
    } else if (wb < 4032) {
      int b = wb - 3456; in = Wt; o = WtC; N = H2; bx = b % 24; by = b / 24;
    } else {
      int b = wb - 4032; in = Wl; o = WlC; N = H2; bx = b % 24; by = b / 24;
    }
    const int f = bx * 64 + (tid & 63);
    const int hc = by * 4 + (tid >> 6);
    bf16x8 ov;
#pragma unroll
    for (int j = 0; j < 8; j++)
      ov[j] = (short)f2bf(in[(size_t)(hc * 8 + j) * N + f]);
    *(bf16x8*)&o[((size_t)hc * N + f) * 8] = ov;
  }
}

// ---------------- shared K-loop: 128x128 tile, K=768, chunked operands -----
DEVINL void mm_kloop(const unsigned short* __restrict__ Ab, int NRA, int MA,
                     int m0, const unsigned short* __restrict__ Bt, int NRB,
                     int n0, unsigned short* As, unsigned short* Bs,
                     f32x4 (&acc)[4][4]) {
  const int tid = threadIdx.x;
  const int lane = tid & 63;
  const int wave = tid >> 6;
  const int q = lane >> 4;
  const int li = lane & 15;
  const int wm = (wave >> 1) * 64;
  const int wn = (wave & 1) * 64;

  int sr[4], skc[4], sra[4];
#pragma unroll
  for (int j = 0; j < 4; j++) {
    int slot = j * 256 + tid;
    skc[j] = slot >> 7;
    sr[j] = slot & 127;
    sra[j] = min(m0 + sr[j], MA - 1);
  }
  auto stage = [&](int kciter) {
#pragma unroll
    for (int j = 0; j < 4; j++) {
      int slot = j * 256 + tid;
      async16(Ab + ((size_t)(kciter + skc[j]) * NRA + sra[j]) * 8,
              (char*)As + slot * 16);
      async16(Bt + ((size_t)(kciter + skc[j]) * NRB + n0 + sr[j]) * 8,
              (char*)Bs + slot * 16);
    }
  };

  stage(0);
  for (int it = 0; it < 12; it++) {
    __syncthreads();  // stage landed
#pragma unroll
    for (int ks = 0; ks < 2; ks++) {
      bf16x8 af[4], bb[4];
#pragma unroll
      for (int mi = 0; mi < 4; mi++)
        af[mi] = *(const bf16x8*)&As[((ks * 4 + q) * 128 + wm + mi * 16 + li) * 8];
#pragma unroll
      for (int ni = 0; ni < 4; ni++)
        bb[ni] = *(const bf16x8*)&Bs[((ks * 4 + q) * 128 + wn + ni * 16 + li) * 8];
#pragma unroll
      for (int mi = 0; mi < 4; mi++)
#pragma unroll
        for (int ni = 0; ni < 4; ni++)
          acc[mi][ni] = MFMA16(af[mi], bb[ni], acc[mi][ni]);
    }
    __syncthreads();  // all reads done
    if (it + 1 < 12) stage((it + 1) * 8);
  }
}

// ---------------- K2: G1+G2 fused (108 blocks) ----------------
__global__ __launch_bounds__(256, 4) void k_mm1(
    const unsigned short* __restrict__ TC, const unsigned short* __restrict__ LC,
    const unsigned short* __restrict__ WtC, const unsigned short* __restrict__ WlC,
    const float* __restrict__ bt, const float* __restrict__ bl,
    unsigned short* __restrict__ TP, unsigned short* __restrict__ LP) {
  __shared__ __align__(16) unsigned short As[8 * 128 * 8];
  __shared__ __align__(16) unsigned short Bs[8 * 128 * 8];
  const int bid = blockIdx.x;
  const int nt = bid % 12, my = bid / 12;
  const bool tok = my < 8;
  const unsigned short* A = tok ? TC : LC;
  const unsigned short* Bt = tok ? WtC : WlC;
  const float* bias = tok ? bt : bl;
  unsigned short* C = tok ? TP : LP;
  const int NRA = tok ? 1024 : 64, MA = tok ? 1024 : 50;
  const int m0 = tok ? my * 128 : 0;
  const int ldc = NRA;
  const int n0 = nt * 128;

  f32x4 acc[4][4];
#pragma unroll
  for (int i = 0; i < 4; i++)
#pragma unroll
    for (int j = 0; j < 4; j++) acc[i][j] = (f32x4){0.f, 0.f, 0.f, 0.f};
  mm_kloop(A, NRA, MA, m0, Bt, H2, n0, As, Bs, acc);

  const int lane = threadIdx.x & 63, wave = threadIdx.x >> 6;
  const int q = lane >> 4, li = lane & 15;
  const int wm = (wave >> 1) * 64, wn = (wave & 1) * 64;
#pragma unroll
  for (int mi = 0; mi < 4; mi++)
#pragma unroll
    for (int rr = 0; rr < 4; rr++) {
      int row = m0 + wm + mi * 16 + q * 4 + rr;
      if (row < MA) {
#pragma unroll
        for (int ni = 0; ni < 4; ni++) {
          int col = n0 + wn + ni * 16 + li;
          C[((size_t)(col >> 3) * ldc + row) * 8 + (col & 7)] =
              f2bf(acc[mi][ni][rr] + bias[col]);
        }
      }
    }
}

// ---------------- K3: G3+G4 (216 blocks) + make_x (9600 blocks) ----------------
__global__ __launch_bounds__(256, 4) void k_mm2(
    const unsigned short* __restrict__ TP, const unsigned short* __restrict__ LP,
    const unsigned short* __restrict__ W1C,
    float* __restrict__ base, float* __restrict__ al,
    unsigned short* __restrict__ XC) {
  __shared__ __align__(16) unsigned short As[8 * 128 * 8];
  __shared__ __align__(16) unsigned short Bs[8 * 128 * 8];
  const int bid = blockIdx.x;
  if (bid < 216) {
    const int nt = bid % 24, my = bid / 24;
    const bool tok = my < 8;
    const unsigned short* A = tok ? TP : LP;
    const unsigned short* Bt = tok ? W1C : W1C + (size_t)96 * H4 * 8;
    float* Cf = tok ? base : al;
    const int NRA = tok ? 1024 : 64, MA = tok ? 1024 : 50;
    const int m0 = tok ? my * 128 : 0;
    const int n0 = nt * 128;

    f32x4 acc[4][4];
#pragma unroll
    for (int i = 0; i < 4; i++)
#pragma unroll
      for (int j = 0; j < 4; j++) acc[i][j] = (f32x4){0.f, 0.f, 0.f, 0.f};
    mm_kloop(A, NRA, MA, m0, Bt, H4, n0, As, Bs, acc);

    const int lane = threadIdx.x & 63, wave = threadIdx.x >> 6;
    const int q = lane >> 4, li = lane & 15;
    const int wm = (wave >> 1) * 64, wn = (wave & 1) * 64;
#pragma unroll
    for (int mi = 0; mi < 4; mi++)
#pragma unroll
      for (int rr = 0; rr < 4; rr++) {
        int row = m0 + wm + mi * 16 + q * 4 + rr;
        if (row < MA) {
#pragma unroll
          for (int ni = 0; ni < 4; ni++) {
            int col = n0 + wn + ni * 16 + li;
            Cf[(size_t)row * H4 + col] = acc[mi][ni][rr];
          }
        }
      }
  } else {
    // make_x: XC[bc][hc][s][8] = tb_chunk(96+hc)[b*512+s] * lb_chunk(96+hc)[bc]
    const int i = bid - 216;           // 0..9599
    const int bc = i / 192;
    const int rem = i % 192;
    const int hc = rem >> 1;
    const int s = (rem & 1) * 256 + threadIdx.x;
    const int b = bc / CC;
    bf16x8 tv = *(const bf16x8*)&TP[((size_t)(96 + hc) * 1024 + b * 512 + s) * 8];
    bf16x8 lv = *(const bf16x8*)&LP[((size_t)(96 + hc) * 64 + bc) * 8];
    bf16x8 o;
#pragma unroll
    for (int j = 0; j < 8; j++)
      o[j] = (short)f2bf(bf2f((unsigned short)tv[j]) * bf2f((unsigned short)lv[j]));
    *(bf16x8*)&XC[(size_t)bc * XC_STRIDE + ((size_t)hc * 512 + s) * 8] = o;
  }
}

// ---------------- K4: G5 scorer (grid 24 x 200) ----------------
// R5 structure (A direct global->register, ping-pong one K-step ahead) +
// T3 minimum-2-phase staging for B: double-buffered LDS, STAGE issued at the
// TOP of each iteration (latency covered by the full compute phase), ONE
// barrier per iteration preceded by counted s_waitcnt vmcnt(8) — retires the
// 4 stage loads, leaves the 8 A-register prefetches in flight across the
// barrier. Per-thread vmem ledger: 8 -> 12 -> 8; never drains to 0 in-loop.

#define STAGE_B4(KC0, BI) do {                                                \
    char* dst_ = (char*)&Bs[BI][0];                                           \
    _Pragma("unroll")                                                         \
    for (int j_ = 0; j_ < 4; j_++) {                                          \
      int slot_ = j_ * 256 + tid;                                             \
      async16(Bt + ((size_t)((KC0) + (slot_ >> 7)) * H4 + n0 + (slot_ & 127)) * 8, \
              dst_ + slot_ * 16);                                             \
    } } while (0)

__global__ __launch_bounds__(256, 4) void k_scorer(
    const unsigned short* __restrict__ XC,   // per-bc slabs [96][512][8]
    const unsigned short* __restrict__ Bt,   // W1p chunked [96][3072][8]
    const float* __restrict__ base, const float* __restrict__ al,
    const float* __restrict__ b1, const float* __restrict__ W2,
    float* __restrict__ out) {
  __shared__ __align__(16) unsigned short Bs[2][8 * 128 * 8];  // 2 x 16 KB
  const int tid = threadIdx.x;
  const int lane = tid & 63;
  const int wave = tid >> 6;
  const int q = lane >> 4;
  const int li = lane & 15;
  const int wm = (wave >> 1) * 64;
  const int wn = (wave & 1) * 64;

  const int n0 = blockIdx.x * 128;
  const int bc = blockIdx.y >> 2;
  const int m0 = (blockIdx.y & 3) * 128;
  const unsigned short* Ab = XC + (size_t)bc * XC_STRIDE;

  // per-mi A fragment base pointers (row part constant; add chunk*4096 elems)
  const unsigned short* ap[4];
#pragma unroll
  for (int mi = 0; mi < 4; mi++)
    ap[mi] = Ab + (size_t)(m0 + wm + mi * 16 + li) * 8;

  f32x4 acc[4][4];
#pragma unroll
  for (int i = 0; i < 4; i++)
#pragma unroll
    for (int j = 0; j < 4; j++) acc[i][j] = (f32x4){0.f, 0.f, 0.f, 0.f};

  // prologue: B tile 0 staged first, then A fragments for steps 0,1.
  // vmcnt(8) retires the 4 stage loads (oldest); af loads stay in flight
  // (compiler inserts its own waits before their MFMA use).
  STAGE_B4(0, 0);
  bf16x8 af0[4], af1[4];
#pragma unroll
  for (int mi = 0; mi < 4; mi++)
    af0[mi] = *(const bf16x8*)(ap[mi] + (size_t)(0 + q) * 4096);
#pragma unroll
  for (int mi = 0; mi < 4; mi++)
    af1[mi] = *(const bf16x8*)(ap[mi] + (size_t)(4 + q) * 4096);
  asm volatile("s_waitcnt vmcnt(8)" ::: "memory");
  BAR();

#pragma unroll 1
  for (int it = 0; it < 12; it++) {
    // issue next tile's staging FIRST — full compute phase covers latency.
    // Writes go to Bs[(it+1)&1]; current reads are from Bs[it&1] (disjoint).
    if (it < 11) STAGE_B4((it + 1) * 8, (it + 1) & 1);
    const unsigned short* Bd = &Bs[it & 1][0];
    bf16x8 bb[4];
    // ---- ks = 0: consume af0, prefetch af0 <- step 2*(it+1)
#pragma unroll
    for (int ni = 0; ni < 4; ni++)
      bb[ni] = *(const bf16x8*)&Bd[((0 + q) * 128 + wn + ni * 16 + li) * 8];
#pragma unroll
    for (int mi = 0; mi < 4; mi++)
#pragma unroll
      for (int ni = 0; ni < 4; ni++)
        acc[mi][ni] = MFMA16(af0[mi], bb[ni], acc[mi][ni]);
    {
      const int cb0 = (it < 11) ? (it + 1) * 8 : 88;  // clamp: keep addr valid
#pragma unroll
      for (int mi = 0; mi < 4; mi++)
        af0[mi] = *(const bf16x8*)(ap[mi] + (size_t)(cb0 + q) * 4096);
    }
    // ---- ks = 1: consume af1, prefetch af1 <- step 2*(it+1)+1
#pragma unroll
    for (int ni = 0; ni < 4; ni++)
      bb[ni] = *(const bf16x8*)&Bd[((4 + q) * 128 + wn + ni * 16 + li) * 8];
#pragma unroll
    for (int mi = 0; mi < 4; mi++)
#pragma unroll
      for (int ni = 0; ni < 4; ni++)
        acc[mi][ni] = MFMA16(af1[mi], bb[ni], acc[mi][ni]);
    {
      const int cb1 = (it < 11) ? (it + 1) * 8 + 4 : 92;
#pragma unroll
      for (int mi = 0; mi < 4; mi++)
        af1[mi] = *(const bf16x8*)(ap[mi] + (size_t)(cb1 + q) * 4096);
    }
    // retire this iteration's 4 stage loads (issued at top — ~full compute
    // phase of cover); keep the 8 af prefetches in flight across the barrier.
    asm volatile("s_waitcnt vmcnt(8)" ::: "memory");
    BAR();
  }

  // epilogue: E = acc + base + al + b1; relu; out += E @ W2 via MFMA.
  // All waves passed the final barrier; scratch in Bs[0] (per-wave regions).
  const int b = bc / CC, c = bc % CC;
  int fcol[4];
  float alb[4];
#pragma unroll
  for (int ni = 0; ni < 4; ni++) {
    int f = n0 + wn + ni * 16 + li;
    fcol[ni] = f;
    alb[ni] = al[(size_t)bc * H4 + f] + b1[f];
  }
  bf16x8 w2f[2];
#pragma unroll
  for (int ks = 0; ks < 2; ks++)
#pragma unroll
    for (int jj = 0; jj < 8; jj++) {
      int f = n0 + wn + ks * 32 + q * 8 + jj;
      float v = (li < 3) ? W2[(size_t)f * 3 + li] : 0.f;
      w2f[ks][jj] = (short)f2bf(v);
    }
  unsigned short* Ew = (unsigned short*)((char*)&Bs[0][0] + wave * 2304);

#pragma unroll
  for (int mi = 0; mi < 4; mi++) {
    float bs[4][4];
#pragma unroll
    for (int rr = 0; rr < 4; rr++) {
      int s_l = m0 + wm + mi * 16 + q * 4 + rr;
      const float* bp = base + (size_t)(b * SS + s_l) * H4;
#pragma unroll
      for (int ni = 0; ni < 4; ni++) bs[ni][rr] = bp[fcol[ni]];
    }
#pragma unroll
    for (int rr = 0; rr < 4; rr++)
#pragma unroll
      for (int ni = 0; ni < 4; ni++) {
        float v = acc[mi][ni][rr] + bs[ni][rr] + alb[ni];
        v = fmaxf(v, 0.f);
        Ew[(q * 4 + rr) * 72 + ni * 16 + li] = f2bf(v);
      }
    f32x4 oc = (f32x4){0.f, 0.f, 0.f, 0.f};
#pragma unroll
    for (int ks = 0; ks < 2; ks++) {
      bf16x8 ef = *(const bf16x8*)&Ew[li * 72 + ks * 32 + q * 8];
      oc = MFMA16(ef, w2f[ks], oc);
    }
#pragma unroll
    for (int rr = 0; rr < 4; rr++) {
      int s_l = m0 + wm + mi * 16 + q * 4 + rr;
      if (li < 3)
        atomicAdd(&out[((size_t)(b * SS + s_l) * CC + c) * 3 + li], oc[rr]);
    }
  }
}

// ---------------- host launch ----------------

extern "C" void kernel_launch(void* const* d_in, const int* in_sizes, int n_in,
                              void* d_out, int out_size, void* d_ws, size_t ws_size,
                              hipStream_t stream) {
  (void)in_sizes; (void)n_in; (void)ws_size; (void)out_size;
  const float* token = (const float*)d_in[0];
  const float* label = (const float*)d_in[1];
  const float* Wt    = (const float*)d_in[2];
  const float* bt    = (const float*)d_in[3];
  const float* Wl    = (const float*)d_in[4];
  const float* bl    = (const float*)d_in[5];
  const float* W1    = (const float*)d_in[6];
  const float* b1    = (const float*)d_in[7];
  const float* W2    = (const float*)d_in[8];
  const float* b2    = (const float*)d_in[9];
  float* out = (float*)d_out;

  char* p = (char*)d_ws;
  auto alloc = [&](size_t bytes) {
    char* r = p;
    p += (bytes + 255) & ~(size_t)255;
    return r;
  };
  unsigned short* TC  = (unsigned short*)alloc((size_t)96 * 1024 * 8 * 2);
  unsigned short* LC  = (unsigned short*)alloc((size_t)96 * 64 * 8 * 2);
  unsigned short* WtC = (unsigned short*)alloc((size_t)96 * 1536 * 8 * 2);
  unsigned short* WlC = (unsigned short*)alloc((size_t)96 * 1536 * 8 * 2);
  unsigned short* W1C = (unsigned short*)alloc((size_t)288 * 3072 * 8 * 2);
  unsigned short* TP  = (unsigned short*)alloc((size_t)192 * 1024 * 8 * 2);
  unsigned short* LP  = (unsigned short*)alloc((size_t)192 * 64 * 8 * 2);
  unsigned short* XC  = (unsigned short*)alloc((size_t)CC * BB * XC_STRIDE * 2);
  float* base = (float*)alloc((size_t)BB * SS * H4 * 4);
  float* al   = (float*)alloc((size_t)BB * CC * H4 * 4);

  // K1: all casts/chunking + out init
  k_prep<<<5316, 256, 0, stream>>>(token, label, b2, Wt, Wl, W1,
                                   TC, LC, out, WtC, WlC, W1C);
  // K2: G1+G2 fused projections
  k_mm1<<<108, 256, 0, stream>>>(TC, LC, WtC, WlC, bt, bl, TP, LP);
  // K3: G3+G4 GEMMs + make_x
  k_mm2<<<9816, 256, 0, stream>>>(TP, LP, W1C, base, al, XC);
  // K4: G5 scorer (A direct-to-register, B LDS double-buffered, stage-at-top)
  k_scorer<<<dim3(24, 200), 256, 0, stream>>>(
      XC, W1C + (size_t)192 * H4 * 8, base, al, b1, W2, out);
}